// Round 5
// baseline (287.727 us; speedup 1.0000x reference)
//
#include <hip/hip_runtime.h>
#include <cstdint>
#include <cstddef>

#define K_CODES 1024
#define D_DIM   64
#define T_SZ    2048
#define N_ROWS  32768
#define BCT     2097152

typedef const __attribute__((address_space(1))) uint32_t* gp1_t;
typedef __attribute__((address_space(3))) uint32_t*       lp3_t;
typedef __attribute__((ext_vector_type(2))) float         f32x2;

// ws layout (bytes):
//   [0,    4096):  hist[1024] int    (zeroed by k_esq_init)
//   [4096, 4104):  loss_sum double   (zeroed by k_esq_init)
//   [8192, 12288): esq[1024] float   (written by k_esq_init)

__global__ __launch_bounds__(256) void k_esq_init(const float* __restrict__ w,
                                                  float* __restrict__ esq,
                                                  int* __restrict__ hist,
                                                  double* __restrict__ loss_sum) {
    const int k = blockIdx.x * 256 + threadIdx.x;   // 0..1023
    hist[k] = 0;
    if (k == 0) loss_sum[0] = 0.0;
    const float4* wr = (const float4*)(w + (size_t)k * D_DIM);
    float s0 = 0.f, s1 = 0.f, s2 = 0.f, s3 = 0.f;
#pragma unroll
    for (int i = 0; i < 16; ++i) {
        const float4 a = wr[i];
        s0 = fmaf(a.x, a.x, s0); s1 = fmaf(a.y, a.y, s1);
        s2 = fmaf(a.z, a.z, s2); s3 = fmaf(a.w, a.w, s3);
    }
    esq[k] = (s0 + s1) + (s2 + s3);
}

// Mega-kernel: argmin over 1024 codes + one-hot rows + straight-through
// quant + fp64 loss partial + histogram. 512 thr = 8 waves; lane = row
// (64 rows/block); wave w owns codes [w*128, w*128+128). Grid 512.
// Row lives in 32 NAMED f32x2 registers (X0..X31, value = -2*x) so the
// compiler cannot demote it to scratch (R3: array form -> VGPR=64 + spill).
__global__ __launch_bounds__(512) void k_argmin(
        const float* __restrict__ in, const float* __restrict__ w,
        const float* __restrict__ esq, int* __restrict__ hist,
        double* __restrict__ loss_sum, float* __restrict__ qout,
        float* __restrict__ enc) {
    __shared__ float lds_w[2][8192];       // 2 x 32KB: 8 waves x 16 codes x 64 f
    __shared__ float lds_esq[K_CODES];     // 4KB
    __shared__ float sm1[8][64], sm2[8][64];
    __shared__ int   si1[8][64], si2[8][64];
    __shared__ int   fin_s[64];
    __shared__ double redd[8];

    const int tid  = threadIdx.x;
    const int lane = tid & 63;
    const int wv   = tid >> 6;
    const int n    = blockIdx.x * 64 + lane;
    const int b    = n >> 11;
    const int t    = n & (T_SZ - 1);
    const size_t base = (size_t)b * (D_DIM * T_SZ) + (size_t)t;

    lds_esq[tid]       = esq[tid];
    lds_esq[tid + 512] = esq[tid + 512];

    // row scaled by -2 (exact pow2), as 32 named f32x2 regs
#define DECLX(I) f32x2 X##I; \
    X##I.x = -2.0f * in[base + (size_t)(2*(I)    ) * T_SZ]; \
    X##I.y = -2.0f * in[base + (size_t)(2*(I) + 1) * T_SZ];
    DECLX(0)  DECLX(1)  DECLX(2)  DECLX(3)  DECLX(4)  DECLX(5)  DECLX(6)  DECLX(7)
    DECLX(8)  DECLX(9)  DECLX(10) DECLX(11) DECLX(12) DECLX(13) DECLX(14) DECLX(15)
    DECLX(16) DECLX(17) DECLX(18) DECLX(19) DECLX(20) DECLX(21) DECLX(22) DECLX(23)
    DECLX(24) DECLX(25) DECLX(26) DECLX(27) DECLX(28) DECLX(29) DECLX(30) DECLX(31)

#define STAGE(CBUF, CC)                                                        \
    {                                                                          \
        _Pragma("unroll")                                                      \
        for (int r = 0; r < 4; ++r) {                                          \
            const int li    = r * 512 + tid;                                   \
            const int wsel  = li >> 8;                                         \
            const int inner = li & 255;                                        \
            const float* g = w + (((size_t)(wsel * 128 + (CC) * 16)) << 6)     \
                               + (size_t)inner * 4;                            \
            float* l = &lds_w[CBUF][li * 4];                                   \
            __builtin_amdgcn_global_load_lds((gp1_t)g, (lp3_t)l, 16, 0, 0);    \
        }                                                                      \
    }

    STAGE(0, 0)
    __syncthreads();

    float m1 = 1e30f, m2v = 1e30f;
    int   i1 = 0,     i2  = 0;
    int   buf = 0;

    // packed 2xfp32 FMA (VOP3P): 2x fp32 rate; compiler won't emit it itself
#define PK(ACC, XV, W0, W1)                                                    \
    {                                                                          \
        f32x2 wv2; wv2.x = (W0); wv2.y = (W1);                                 \
        asm("v_pk_fma_f32 %0, %1, %2, %0" : "+v"(ACC) : "v"(XV), "v"(wv2));    \
    }
#define DOTQ(J, XA, XB, ACCA, ACCB)                                            \
    { const float4 q = wr4[J]; PK(ACCA, XA, q.x, q.y) PK(ACCB, XB, q.z, q.w) }
#define DOT_ALL                                                                \
    DOTQ(0,  X0,  X1,  acc0, acc1) DOTQ(1,  X2,  X3,  acc2, acc3)              \
    DOTQ(2,  X4,  X5,  acc0, acc1) DOTQ(3,  X6,  X7,  acc2, acc3)              \
    DOTQ(4,  X8,  X9,  acc0, acc1) DOTQ(5,  X10, X11, acc2, acc3)              \
    DOTQ(6,  X12, X13, acc0, acc1) DOTQ(7,  X14, X15, acc2, acc3)              \
    DOTQ(8,  X16, X17, acc0, acc1) DOTQ(9,  X18, X19, acc2, acc3)              \
    DOTQ(10, X20, X21, acc0, acc1) DOTQ(11, X22, X23, acc2, acc3)              \
    DOTQ(12, X24, X25, acc0, acc1) DOTQ(13, X26, X27, acc2, acc3)              \
    DOTQ(14, X28, X29, acc0, acc1) DOTQ(15, X30, X31, acc2, acc3)

    for (int c = 0; c < 8; ++c) {
        if (c < 7) STAGE(buf ^ 1, c + 1)
        const int kb = wv * 128 + c * 16;
#pragma unroll 4
        for (int kk = 0; kk < 16; ++kk) {
            const int k = kb + kk;
            const float4* wr4 = (const float4*)&lds_w[buf][(wv * 16 + kk) * 64];
            f32x2 acc0; acc0.x = lds_esq[k]; acc0.y = 0.f;
            f32x2 acc1 = {0.f, 0.f}, acc2 = {0.f, 0.f}, acc3 = {0.f, 0.f};
            DOT_ALL
            const float dist = ((acc0.x + acc0.y) + (acc1.x + acc1.y))
                             + ((acc2.x + acc2.y) + (acc3.x + acc3.y));
            if (dist < m1)       { m2v = m1; i2 = i1; m1 = dist; i1 = k; }
            else if (dist < m2v) { m2v = dist; i2 = k; }
        }
        __syncthreads();   // drains STAGE vmcnt + protects buf swap
        buf ^= 1;
    }

    sm1[wv][lane] = m1;  sm2[wv][lane] = m2v;
    si1[wv][lane] = i1;  si2[wv][lane] = i2;
    __syncthreads();

    if (wv == 0) {
        for (int s = 1; s < 8; ++s) {   // ascending k; '<' keeps lowest idx
            const float b1 = sm1[s][lane], b2 = sm2[s][lane];
            const int   j1 = si1[s][lane], j2 = si2[s][lane];
            if (b1 < m1) {
                m2v = (b2 < m1) ? b2 : m1;
                i2  = (b2 < m1) ? j2 : i1;
                m1 = b1; i1 = j1;
            } else if (b1 < m2v) {
                m2v = b1; i2 = j1;
            }
        }
        // fp64 recheck of top-2 (decides like a float64 reference)
        const float* w1 = w + ((size_t)i1 << 6);
        const float* w2 = w + ((size_t)i2 << 6);
        double v1 = 0.0, v2 = 0.0;
#define RC2(XV, D0)                                                            \
    {                                                                          \
        const double x0 = -0.5 * (double)XV.x, x1 = -0.5 * (double)XV.y;       \
        const double a0 = (double)w1[D0], a1 = (double)w1[(D0) + 1];           \
        const double c0 = (double)w2[D0], c1 = (double)w2[(D0) + 1];           \
        v1 += a0 * (a0 - 2.0 * x0) + a1 * (a1 - 2.0 * x1);                     \
        v2 += c0 * (c0 - 2.0 * x0) + c1 * (c1 - 2.0 * x1);                     \
    }
        RC2(X0, 0)   RC2(X1, 2)   RC2(X2, 4)   RC2(X3, 6)
        RC2(X4, 8)   RC2(X5, 10)  RC2(X6, 12)  RC2(X7, 14)
        RC2(X8, 16)  RC2(X9, 18)  RC2(X10, 20) RC2(X11, 22)
        RC2(X12, 24) RC2(X13, 26) RC2(X14, 28) RC2(X15, 30)
        RC2(X16, 32) RC2(X17, 34) RC2(X18, 36) RC2(X19, 38)
        RC2(X20, 40) RC2(X21, 42) RC2(X22, 44) RC2(X23, 46)
        RC2(X24, 48) RC2(X25, 50) RC2(X26, 52) RC2(X27, 54)
        RC2(X28, 56) RC2(X29, 58) RC2(X30, 60) RC2(X31, 62)
        int fin;
        if (v1 < v2)      fin = i1;
        else if (v2 < v1) fin = i2;
        else              fin = (i1 < i2) ? i1 : i2;

        fin_s[lane] = fin;
        atomicAdd(&hist[fin], 1);
    }
    __syncthreads();

    // ---- fused epilogue ----
    const int f_own = fin_s[lane];
    const float* wr = w + ((size_t)f_own << 6);
    float* qbase = qout + (size_t)b * (D_DIM * T_SZ) + (size_t)t;
    double sq = 0.0;

#define QS2(XV, Q0, Q1, C)                                                     \
    {                                                                          \
        const float x0 = -0.5f * XV.x, x1 = -0.5f * XV.y;                      \
        const float d0 = (Q0)-x0, d1 = (Q1)-x1;                                \
        qbase[(size_t)(C)*T_SZ]       = x0 + d0;                               \
        qbase[(size_t)((C) + 1)*T_SZ] = x1 + d1;                               \
        sq = fma((double)d0, (double)d0, sq);                                  \
        sq = fma((double)d1, (double)d1, sq);                                  \
    }
#define QCASE(W, XA, XB, XC, XD)                                               \
    {                                                                          \
        const float4 qa = *(const float4*)(wr + (W)*8);                        \
        const float4 qb = *(const float4*)(wr + (W)*8 + 4);                    \
        QS2(XA, qa.x, qa.y, (W)*8 + 0) QS2(XB, qa.z, qa.w, (W)*8 + 2)          \
        QS2(XC, qb.x, qb.y, (W)*8 + 4) QS2(XD, qb.z, qb.w, (W)*8 + 6)          \
    }
    switch (wv) {
        case 0: QCASE(0, X0,  X1,  X2,  X3)  break;
        case 1: QCASE(1, X4,  X5,  X6,  X7)  break;
        case 2: QCASE(2, X8,  X9,  X10, X11) break;
        case 3: QCASE(3, X12, X13, X14, X15) break;
        case 4: QCASE(4, X16, X17, X18, X19) break;
        case 5: QCASE(5, X20, X21, X22, X23) break;
        case 6: QCASE(6, X24, X25, X26, X27) break;
        case 7: QCASE(7, X28, X29, X30, X31) break;
    }

    for (int off = 32; off > 0; off >>= 1) sq += __shfl_down(sq, off);
    if (lane == 0) redd[wv] = sq;

    // full one-hot rows: wave w writes rows w*8..w*8+8 (float2 stores)
#pragma unroll 1
    for (int rr = 0; rr < 8; ++rr) {
        const int row = wv * 8 + rr;
        const int f = fin_s[row];
        float* ebase = enc + (((size_t)(blockIdx.x * 64 + row)) << 10);
#pragma unroll
        for (int j = 0; j < 8; ++j) {
            const int col = j * 128 + lane * 2;
            float2 v;
            v.x = (col == f)     ? 1.0f : 0.0f;
            v.y = (col + 1 == f) ? 1.0f : 0.0f;
            *(float2*)(ebase + col) = v;
        }
    }

    __syncthreads();
    if (tid == 0) {
        double s = 0.0;
#pragma unroll
        for (int i = 0; i < 8; ++i) s += redd[i];
        atomicAdd(loss_sum, s);
    }
}

__global__ __launch_bounds__(256) void k_final(const int* __restrict__ hist,
                                               const double* __restrict__ loss_sum,
                                               float* __restrict__ out_loss,
                                               float* __restrict__ out_perp) {
    __shared__ double red[256];
    const int tid = threadIdx.x;
    double h = 0.0;
    for (int k = tid; k < K_CODES; k += 256) {
        const double p = (double)hist[k] / (double)N_ROWS;
        h += p * log(p + 1e-10);
    }
    red[tid] = h;
    __syncthreads();
#pragma unroll
    for (int st = 128; st > 0; st >>= 1) {
        if (tid < st) red[tid] += red[tid + st];
        __syncthreads();
    }
    if (tid == 0) {
        out_perp[0] = (float)exp(-red[0]);
        const double mean = loss_sum[0] / (double)BCT;
        out_loss[0] = (float)(1.25 * mean);  // q_latent + 0.25*e_latent
    }
}

extern "C" void kernel_launch(void* const* d_in, const int* in_sizes, int n_in,
                              void* d_out, int out_size, void* d_ws, size_t ws_size,
                              hipStream_t stream) {
    const float* in = (const float*)d_in[0];
    const float* w  = (const float*)d_in[1];

    float* out      = (float*)d_out;
    float* out_loss = out;                 // [0]
    float* out_q    = out + 1;             // [1, 1+BCT)
    float* out_perp = out + 1 + BCT;       // [1+BCT]
    float* out_enc  = out + 2 + BCT;       // [2+BCT, ...)

    char*   ws       = (char*)d_ws;
    int*    ws_hist  = (int*)ws;
    double* ws_loss  = (double*)(ws + 4096);
    float*  ws_esq   = (float*)(ws + 8192);

    k_esq_init<<<4,   256, 0, stream>>>(w, ws_esq, ws_hist, ws_loss);
    k_argmin  <<<512, 512, 0, stream>>>(in, w, ws_esq, ws_hist, ws_loss,
                                        out_q, out_enc);
    k_final   <<<1,   256, 0, stream>>>(ws_hist, ws_loss, out_loss, out_perp);
}

// Round 6
// 230.872 us; speedup vs baseline: 1.2463x; 1.2463x over previous
//
#include <hip/hip_runtime.h>
#include <cstdint>
#include <cstddef>

#define K_CODES 1024
#define D_DIM   64
#define T_SZ    2048
#define N_ROWS  32768
#define BCT     2097152

typedef const __attribute__((address_space(1))) uint32_t* gp1_t;
typedef __attribute__((address_space(3))) uint32_t*       lp3_t;
typedef __attribute__((ext_vector_type(2))) float         f32x2;

// ws layout (bytes):
//   [0,    4096):  hist[1024] int    (zeroed by k_esq_init)
//   [4096, 4104):  loss_sum double   (zeroed by k_esq_init)
//   [8192, 12288): esq[1024] float   (written by k_esq_init)

__global__ __launch_bounds__(256) void k_esq_init(const float* __restrict__ w,
                                                  float* __restrict__ esq,
                                                  int* __restrict__ hist,
                                                  double* __restrict__ loss_sum) {
    const int k = blockIdx.x * 256 + threadIdx.x;   // 0..1023
    hist[k] = 0;
    if (k == 0) loss_sum[0] = 0.0;
    const float4* wr = (const float4*)(w + (size_t)k * D_DIM);
    float s0 = 0.f, s1 = 0.f, s2 = 0.f, s3 = 0.f;
#pragma unroll
    for (int i = 0; i < 16; ++i) {
        const float4 a = wr[i];
        s0 = fmaf(a.x, a.x, s0); s1 = fmaf(a.y, a.y, s1);
        s2 = fmaf(a.z, a.z, s2); s3 = fmaf(a.w, a.w, s3);
    }
    esq[k] = (s0 + s1) + (s2 + s3);
}

// Mega-kernel: argmin over 1024 codes + one-hot rows + straight-through
// quant + fp64 loss partial + histogram. 512 thr = 8 waves; lane = row
// (64 rows/block); wave w owns codes [w*128, w*128+128). Grid 512.
// Row lives in 32 NAMED f32x2 registers (X0..X31, value = -2*x), each
// PINNED via empty inline asm: R5 showed the compiler REMATERIALIZES
// const-__restrict__ loads instead of keeping them live (VGPR=68 with 64
// row values!) -> re-loads from global in the k-loop, latency-bound.
// An asm-defined value cannot be rematerialized -> stays in VGPRs.
// __launch_bounds__(512,4): 4 waves/EU -> VGPR cap 128 (fits ~110 live),
// matches the LDS-capped 2 blocks/CU.
__global__ __launch_bounds__(512, 4) void k_argmin(
        const float* __restrict__ in, const float* __restrict__ w,
        const float* __restrict__ esq, int* __restrict__ hist,
        double* __restrict__ loss_sum, float* __restrict__ qout,
        float* __restrict__ enc) {
    __shared__ float lds_w[2][8192];       // 2 x 32KB: 8 waves x 16 codes x 64 f
    __shared__ float lds_esq[K_CODES];     // 4KB
    __shared__ float sm1[8][64], sm2[8][64];
    __shared__ int   si1[8][64], si2[8][64];
    __shared__ int   fin_s[64];
    __shared__ double redd[8];

    const int tid  = threadIdx.x;
    const int lane = tid & 63;
    const int wv   = tid >> 6;
    const int n    = blockIdx.x * 64 + lane;
    const int b    = n >> 11;
    const int t    = n & (T_SZ - 1);
    const size_t base = (size_t)b * (D_DIM * T_SZ) + (size_t)t;

    lds_esq[tid]       = esq[tid];
    lds_esq[tid + 512] = esq[tid + 512];

    // row scaled by -2 (exact pow2), as 32 named f32x2 regs, remat-pinned
#define DECLX(I) f32x2 X##I; \
    X##I.x = -2.0f * in[base + (size_t)(2*(I)    ) * T_SZ]; \
    X##I.y = -2.0f * in[base + (size_t)(2*(I) + 1) * T_SZ]; \
    asm("" : "+v"(X##I));
    DECLX(0)  DECLX(1)  DECLX(2)  DECLX(3)  DECLX(4)  DECLX(5)  DECLX(6)  DECLX(7)
    DECLX(8)  DECLX(9)  DECLX(10) DECLX(11) DECLX(12) DECLX(13) DECLX(14) DECLX(15)
    DECLX(16) DECLX(17) DECLX(18) DECLX(19) DECLX(20) DECLX(21) DECLX(22) DECLX(23)
    DECLX(24) DECLX(25) DECLX(26) DECLX(27) DECLX(28) DECLX(29) DECLX(30) DECLX(31)

#define STAGE(CBUF, CC)                                                        \
    {                                                                          \
        _Pragma("unroll")                                                      \
        for (int r = 0; r < 4; ++r) {                                          \
            const int li    = r * 512 + tid;                                   \
            const int wsel  = li >> 8;                                         \
            const int inner = li & 255;                                        \
            const float* g = w + (((size_t)(wsel * 128 + (CC) * 16)) << 6)     \
                               + (size_t)inner * 4;                            \
            float* l = &lds_w[CBUF][li * 4];                                   \
            __builtin_amdgcn_global_load_lds((gp1_t)g, (lp3_t)l, 16, 0, 0);    \
        }                                                                      \
    }

    STAGE(0, 0)
    __syncthreads();

    float m1 = 1e30f, m2v = 1e30f;
    int   i1 = 0,     i2  = 0;
    int   buf = 0;

    // packed 2xfp32 FMA (VOP3P): 2x fp32 rate; compiler won't emit it itself
#define PK(ACC, XV, W0, W1)                                                    \
    {                                                                          \
        f32x2 wv2; wv2.x = (W0); wv2.y = (W1);                                 \
        asm("v_pk_fma_f32 %0, %1, %2, %0" : "+v"(ACC) : "v"(XV), "v"(wv2));    \
    }
#define DOTQ(J, XA, XB, ACCA, ACCB)                                            \
    { const float4 q = wr4[J]; PK(ACCA, XA, q.x, q.y) PK(ACCB, XB, q.z, q.w) }
#define DOT_ALL                                                                \
    DOTQ(0,  X0,  X1,  acc0, acc1) DOTQ(1,  X2,  X3,  acc2, acc3)              \
    DOTQ(2,  X4,  X5,  acc0, acc1) DOTQ(3,  X6,  X7,  acc2, acc3)              \
    DOTQ(4,  X8,  X9,  acc0, acc1) DOTQ(5,  X10, X11, acc2, acc3)              \
    DOTQ(6,  X12, X13, acc0, acc1) DOTQ(7,  X14, X15, acc2, acc3)              \
    DOTQ(8,  X16, X17, acc0, acc1) DOTQ(9,  X18, X19, acc2, acc3)              \
    DOTQ(10, X20, X21, acc0, acc1) DOTQ(11, X22, X23, acc2, acc3)              \
    DOTQ(12, X24, X25, acc0, acc1) DOTQ(13, X26, X27, acc2, acc3)              \
    DOTQ(14, X28, X29, acc0, acc1) DOTQ(15, X30, X31, acc2, acc3)

    for (int c = 0; c < 8; ++c) {
        if (c < 7) STAGE(buf ^ 1, c + 1)
        const int kb = wv * 128 + c * 16;
#pragma unroll 4
        for (int kk = 0; kk < 16; ++kk) {
            const int k = kb + kk;
            const float4* wr4 = (const float4*)&lds_w[buf][(wv * 16 + kk) * 64];
            f32x2 acc0; acc0.x = lds_esq[k]; acc0.y = 0.f;
            f32x2 acc1 = {0.f, 0.f}, acc2 = {0.f, 0.f}, acc3 = {0.f, 0.f};
            DOT_ALL
            const float dist = ((acc0.x + acc0.y) + (acc1.x + acc1.y))
                             + ((acc2.x + acc2.y) + (acc3.x + acc3.y));
            if (dist < m1)       { m2v = m1; i2 = i1; m1 = dist; i1 = k; }
            else if (dist < m2v) { m2v = dist; i2 = k; }
        }
        __syncthreads();   // drains STAGE vmcnt + protects buf swap
        buf ^= 1;
    }

    sm1[wv][lane] = m1;  sm2[wv][lane] = m2v;
    si1[wv][lane] = i1;  si2[wv][lane] = i2;
    __syncthreads();

    if (wv == 0) {
        for (int s = 1; s < 8; ++s) {   // ascending k; '<' keeps lowest idx
            const float b1 = sm1[s][lane], b2 = sm2[s][lane];
            const int   j1 = si1[s][lane], j2 = si2[s][lane];
            if (b1 < m1) {
                m2v = (b2 < m1) ? b2 : m1;
                i2  = (b2 < m1) ? j2 : i1;
                m1 = b1; i1 = j1;
            } else if (b1 < m2v) {
                m2v = b1; i2 = j1;
            }
        }
        // fp64 recheck of top-2 (decides like a float64 reference)
        const float* w1 = w + ((size_t)i1 << 6);
        const float* w2 = w + ((size_t)i2 << 6);
        double v1 = 0.0, v2 = 0.0;
#define RC2(XV, D0)                                                            \
    {                                                                          \
        const double x0 = -0.5 * (double)XV.x, x1 = -0.5 * (double)XV.y;       \
        const double a0 = (double)w1[D0], a1 = (double)w1[(D0) + 1];           \
        const double c0 = (double)w2[D0], c1 = (double)w2[(D0) + 1];           \
        v1 += a0 * (a0 - 2.0 * x0) + a1 * (a1 - 2.0 * x1);                     \
        v2 += c0 * (c0 - 2.0 * x0) + c1 * (c1 - 2.0 * x1);                     \
    }
        RC2(X0, 0)   RC2(X1, 2)   RC2(X2, 4)   RC2(X3, 6)
        RC2(X4, 8)   RC2(X5, 10)  RC2(X6, 12)  RC2(X7, 14)
        RC2(X8, 16)  RC2(X9, 18)  RC2(X10, 20) RC2(X11, 22)
        RC2(X12, 24) RC2(X13, 26) RC2(X14, 28) RC2(X15, 30)
        RC2(X16, 32) RC2(X17, 34) RC2(X18, 36) RC2(X19, 38)
        RC2(X20, 40) RC2(X21, 42) RC2(X22, 44) RC2(X23, 46)
        RC2(X24, 48) RC2(X25, 50) RC2(X26, 52) RC2(X27, 54)
        RC2(X28, 56) RC2(X29, 58) RC2(X30, 60) RC2(X31, 62)
        int fin;
        if (v1 < v2)      fin = i1;
        else if (v2 < v1) fin = i2;
        else              fin = (i1 < i2) ? i1 : i2;

        fin_s[lane] = fin;
        atomicAdd(&hist[fin], 1);
    }
    __syncthreads();

    // ---- fused epilogue ----
    const int f_own = fin_s[lane];
    const float* wr = w + ((size_t)f_own << 6);
    float* qbase = qout + (size_t)b * (D_DIM * T_SZ) + (size_t)t;
    double sq = 0.0;

#define QS2(XV, Q0, Q1, C)                                                     \
    {                                                                          \
        const float x0 = -0.5f * XV.x, x1 = -0.5f * XV.y;                      \
        const float d0 = (Q0)-x0, d1 = (Q1)-x1;                                \
        qbase[(size_t)(C)*T_SZ]       = x0 + d0;                               \
        qbase[(size_t)((C) + 1)*T_SZ] = x1 + d1;                               \
        sq = fma((double)d0, (double)d0, sq);                                  \
        sq = fma((double)d1, (double)d1, sq);                                  \
    }
#define QCASE(W, XA, XB, XC, XD)                                               \
    {                                                                          \
        const float4 qa = *(const float4*)(wr + (W)*8);                        \
        const float4 qb = *(const float4*)(wr + (W)*8 + 4);                    \
        QS2(XA, qa.x, qa.y, (W)*8 + 0) QS2(XB, qa.z, qa.w, (W)*8 + 2)          \
        QS2(XC, qb.x, qb.y, (W)*8 + 4) QS2(XD, qb.z, qb.w, (W)*8 + 6)          \
    }
    switch (wv) {
        case 0: QCASE(0, X0,  X1,  X2,  X3)  break;
        case 1: QCASE(1, X4,  X5,  X6,  X7)  break;
        case 2: QCASE(2, X8,  X9,  X10, X11) break;
        case 3: QCASE(3, X12, X13, X14, X15) break;
        case 4: QCASE(4, X16, X17, X18, X19) break;
        case 5: QCASE(5, X20, X21, X22, X23) break;
        case 6: QCASE(6, X24, X25, X26, X27) break;
        case 7: QCASE(7, X28, X29, X30, X31) break;
    }

    for (int off = 32; off > 0; off >>= 1) sq += __shfl_down(sq, off);
    if (lane == 0) redd[wv] = sq;

    // full one-hot rows: wave w writes rows w*8..w*8+8 (float2 stores)
#pragma unroll 1
    for (int rr = 0; rr < 8; ++rr) {
        const int row = wv * 8 + rr;
        const int f = fin_s[row];
        float* ebase = enc + (((size_t)(blockIdx.x * 64 + row)) << 10);
#pragma unroll
        for (int j = 0; j < 8; ++j) {
            const int col = j * 128 + lane * 2;
            float2 v;
            v.x = (col == f)     ? 1.0f : 0.0f;
            v.y = (col + 1 == f) ? 1.0f : 0.0f;
            *(float2*)(ebase + col) = v;
        }
    }

    __syncthreads();
    if (tid == 0) {
        double s = 0.0;
#pragma unroll
        for (int i = 0; i < 8; ++i) s += redd[i];
        atomicAdd(loss_sum, s);
    }
}

__global__ __launch_bounds__(256) void k_final(const int* __restrict__ hist,
                                               const double* __restrict__ loss_sum,
                                               float* __restrict__ out_loss,
                                               float* __restrict__ out_perp) {
    __shared__ double red[256];
    const int tid = threadIdx.x;
    double h = 0.0;
    for (int k = tid; k < K_CODES; k += 256) {
        const double p = (double)hist[k] / (double)N_ROWS;
        h += p * log(p + 1e-10);
    }
    red[tid] = h;
    __syncthreads();
#pragma unroll
    for (int st = 128; st > 0; st >>= 1) {
        if (tid < st) red[tid] += red[tid + st];
        __syncthreads();
    }
    if (tid == 0) {
        out_perp[0] = (float)exp(-red[0]);
        const double mean = loss_sum[0] / (double)BCT;
        out_loss[0] = (float)(1.25 * mean);  // q_latent + 0.25*e_latent
    }
}

extern "C" void kernel_launch(void* const* d_in, const int* in_sizes, int n_in,
                              void* d_out, int out_size, void* d_ws, size_t ws_size,
                              hipStream_t stream) {
    const float* in = (const float*)d_in[0];
    const float* w  = (const float*)d_in[1];

    float* out      = (float*)d_out;
    float* out_loss = out;                 // [0]
    float* out_q    = out + 1;             // [1, 1+BCT)
    float* out_perp = out + 1 + BCT;       // [1+BCT]
    float* out_enc  = out + 2 + BCT;       // [2+BCT, ...)

    char*   ws       = (char*)d_ws;
    int*    ws_hist  = (int*)ws;
    double* ws_loss  = (double*)(ws + 4096);
    float*  ws_esq   = (float*)(ws + 8192);

    k_esq_init<<<4,   256, 0, stream>>>(w, ws_esq, ws_hist, ws_loss);
    k_argmin  <<<512, 512, 0, stream>>>(in, w, ws_esq, ws_hist, ws_loss,
                                        out_q, out_enc);
    k_final   <<<1,   256, 0, stream>>>(ws_hist, ws_loss, out_loss, out_perp);
}

// Round 7
// 207.813 us; speedup vs baseline: 1.3845x; 1.1110x over previous
//
#include <hip/hip_runtime.h>
#include <cstdint>
#include <cstddef>

#define K_CODES 1024
#define D_DIM   64
#define T_SZ    2048
#define N_ROWS  32768
#define BCT     2097152

typedef const __attribute__((address_space(1))) uint32_t* gp1_t;
typedef __attribute__((address_space(3))) uint32_t*       lp3_t;
typedef __attribute__((ext_vector_type(8))) short         short8;  // 8 bf16
typedef __attribute__((ext_vector_type(4))) float         f32x4;
typedef __attribute__((ext_vector_type(4))) int           i32x4;

// ws layout (bytes):
//   [0,     4096):   hist[1024] int     (zeroed by k_prep)
//   [4096,  4104):   loss_sum double    (zeroed by k_prep)
//   [8192,  12288):  esq[1024] float
//   [16384, 278528): Wpack bf16 [64ct][2ks][2hl][64lane][8j] ushort (256KB)

__device__ __forceinline__ ushort bf16_rne(float f) {
    uint32_t u = __builtin_bit_cast(uint32_t, f);
    u += 0x7FFFu + ((u >> 16) & 1u);
    return (ushort)(u >> 16);
}
__device__ __forceinline__ float bf16_f(ushort h) {
    uint32_t u = ((uint32_t)h) << 16;
    return __builtin_bit_cast(float, u);
}

// One thread per code: esq (fp64), zero hist/loss, pack W into MFMA
// B-fragment layout as bf16 hi/lo (w = hi + lo, split error ~2^-18).
__global__ __launch_bounds__(256) void k_prep(const float* __restrict__ w,
                                              float* __restrict__ esq,
                                              ushort* __restrict__ wpack,
                                              int* __restrict__ hist,
                                              double* __restrict__ loss_sum) {
    const int k = blockIdx.x * 256 + threadIdx.x;   // 0..1023
    hist[k] = 0;
    if (k == 0) loss_sum[0] = 0.0;
    const int ct = k >> 4, cl = k & 15;
    double s = 0.0;
    for (int d = 0; d < 64; ++d) {
        const float x = w[k * 64 + d];
        s = fma((double)x, (double)x, s);
        const ushort hi = bf16_rne(x);
        const ushort lo = bf16_rne(x - bf16_f(hi));
        const int ks = d >> 5, g = (d >> 3) & 3, j = d & 7;
        const int lane = g * 16 + cl;
        const size_t base = ((size_t)(ct * 2 + ks)) * 2;
        wpack[((base + 0) * 64 + lane) * 8 + j] = hi;
        wpack[((base + 1) * 64 + lane) * 8 + j] = lo;
    }
    esq[k] = (float)s;
}

// MFMA mega-kernel: 256 blocks x 512 thr (8 waves). Block = 128 rows x all
// 1024 codes. Wave w owns one 16-row A-tile (rows n0+w*16..+16). W streamed
// as 8 chunks of 8 col-tiles (32KB), double-buffered via global_load_lds.
// Distances via 3 bf16-split MFMAs (err ~1e-7); val = x.w - esq/2 maximized
// (== argmin dist). Top-2 tracked per row, merged across the 16 lanes of a
// col-group, fp64 recheck decides the final index.
__global__ __launch_bounds__(512) void k_argmin(
        const float* __restrict__ in, const float* __restrict__ w,
        const float* __restrict__ esq, const ushort* __restrict__ wpack,
        int* __restrict__ hist, double* __restrict__ loss_sum,
        float* __restrict__ qout, float* __restrict__ enc) {
    __shared__ __align__(16) ushort lds_b[2][16384];   // 2 x 32KB
    __shared__ float  lds_esq[K_CODES];                // 4KB
    __shared__ int    smem_i1[128], smem_i2[128];
    __shared__ int    fin_s[128];
    __shared__ double redd[8];

    const int tid  = threadIdx.x;
    const int lane = tid & 63;
    const int wv   = tid >> 6;
    const int cl   = lane & 15;     // col within tile / row within A-tile
    const int g    = lane >> 4;     // k-group
    const int n0   = blockIdx.x * 128;
    const int b    = n0 >> 11;
    const int t0   = n0 & (T_SZ - 1);

    lds_esq[tid]       = esq[tid];
    lds_esq[tid + 512] = esq[tid + 512];

    // ---- A fragments: row = l&15, k = g*8+j (same map used for B ->
    // any shared k-permutation cancels in the contraction) ----
    const int t_row = t0 + wv * 16 + cl;
    short8 ah[2], al[2];
#pragma unroll
    for (int ks = 0; ks < 2; ++ks) {
        short8 h, l;
#pragma unroll
        for (int j = 0; j < 8; ++j) {
            const int d = ks * 32 + g * 8 + j;
            const float x = in[(size_t)b * 131072 + (size_t)d * T_SZ + t_row];
            const ushort hb = bf16_rne(x);
            h[j] = (short)hb;
            l[j] = (short)bf16_rne(x - bf16_f(hb));
        }
        ah[ks] = h;
        al[ks] = l;
    }

#define STAGEW(BUF, CH)                                                        \
    {                                                                          \
        _Pragma("unroll")                                                      \
        for (int r = 0; r < 4; ++r) {                                          \
            const int li = r * 512 + tid;                                      \
            const ushort* gsrc = wpack + (size_t)(CH)*16384 + (size_t)li * 8;  \
            ushort* ldst = &lds_b[BUF][li * 8];                                \
            __builtin_amdgcn_global_load_lds((gp1_t)gsrc, (lp3_t)ldst, 16, 0, 0);\
        }                                                                      \
    }

    STAGEW(0, 0)
    __syncthreads();

    f32x4 m1v = {-1e30f, -1e30f, -1e30f, -1e30f};
    f32x4 m2v = {-1e30f, -1e30f, -1e30f, -1e30f};
    i32x4 i1v = {0, 0, 0, 0};
    i32x4 i2v = {0, 0, 0, 0};

    int buf = 0;
    for (int ch = 0; ch < 8; ++ch) {
        if (ch < 7) STAGEW(buf ^ 1, ch + 1)
#pragma unroll
        for (int ctl = 0; ctl < 8; ++ctl) {
            const int ct = ch * 8 + ctl;
            const int c  = ct * 16 + cl;
            const float e2 = -0.5f * lds_esq[c];
            f32x4 accP = {e2, e2, e2, e2};
            f32x4 accQ = {0.f, 0.f, 0.f, 0.f};
#pragma unroll
            for (int ks = 0; ks < 2; ++ks) {
                const short8 bh = *(const short8*)&lds_b[buf][(((ctl * 2 + ks) * 2 + 0) * 64 + lane) * 8];
                const short8 bl = *(const short8*)&lds_b[buf][(((ctl * 2 + ks) * 2 + 1) * 64 + lane) * 8];
                accP = __builtin_amdgcn_mfma_f32_16x16x32_bf16(ah[ks], bh, accP, 0, 0, 0);
                accQ = __builtin_amdgcn_mfma_f32_16x16x32_bf16(ah[ks], bl, accQ, 0, 0, 0);
                accQ = __builtin_amdgcn_mfma_f32_16x16x32_bf16(al[ks], bh, accQ, 0, 0, 0);
            }
            // track top-2 (maximize val; ascending c + strict '>' keeps
            // lowest index on ties, matching jnp.argmin after negation)
#pragma unroll
            for (int reg = 0; reg < 4; ++reg) {
                const float v = accP[reg] + accQ[reg];
                const bool gt1 = v > m1v[reg];
                const bool gt2 = v > m2v[reg];
                const float nm2 = gt1 ? m1v[reg] : (gt2 ? v : m2v[reg]);
                const int   ni2 = gt1 ? i1v[reg] : (gt2 ? c : i2v[reg]);
                m1v[reg] = gt1 ? v : m1v[reg];
                i1v[reg] = gt1 ? c : i1v[reg];
                m2v[reg] = nm2;
                i2v[reg] = ni2;
            }
        }
        __syncthreads();   // drains STAGE vmcnt + protects buf swap
        buf ^= 1;
    }

    // ---- merge top-2 across the 16 lanes of each col-group ----
#pragma unroll
    for (int off = 1; off < 16; off <<= 1) {
#pragma unroll
        for (int reg = 0; reg < 4; ++reg) {
            const float pm1 = __shfl_xor(m1v[reg], off);
            const int   pi1 = __shfl_xor(i1v[reg], off);
            const float pm2 = __shfl_xor(m2v[reg], off);
            const int   pi2 = __shfl_xor(i2v[reg], off);
            const bool ours = (m1v[reg] > pm1) ||
                              (m1v[reg] == pm1 && i1v[reg] < pi1);
            float nm1, nm2; int ni1, ni2;
            if (ours) {
                nm1 = m1v[reg]; ni1 = i1v[reg];
                const bool pb = (pm1 > m2v[reg]) ||
                                (pm1 == m2v[reg] && pi1 < i2v[reg]);
                nm2 = pb ? pm1 : m2v[reg];
                ni2 = pb ? pi1 : i2v[reg];
            } else {
                nm1 = pm1; ni1 = pi1;
                const bool ob = (m1v[reg] > pm2) ||
                                (m1v[reg] == pm2 && i1v[reg] < pi2);
                nm2 = ob ? m1v[reg] : pm2;
                ni2 = ob ? i1v[reg] : pi2;
            }
            m1v[reg] = nm1; i1v[reg] = ni1;
            m2v[reg] = nm2; i2v[reg] = ni2;
        }
    }
    if (cl == 0) {   // one writer per col-group: rows g*4+reg
#pragma unroll
        for (int reg = 0; reg < 4; ++reg) {
            smem_i1[wv * 16 + g * 4 + reg] = i1v[reg];
            smem_i2[wv * 16 + g * 4 + reg] = i2v[reg];
        }
    }
    __syncthreads();

    // ---- fp64 recheck of top-2 (float64-reference decision) ----
    if (lane < 16) {
        const int rloc = wv * 16 + lane;
        const int ii1 = smem_i1[rloc], ii2 = smem_i2[rloc];
        const int t = t0 + rloc;
        double v1 = 0.0, v2 = 0.0;
        for (int d = 0; d < 64; ++d) {
            const double x = (double)in[(size_t)b * 131072 + (size_t)d * T_SZ + t];
            const double a = (double)w[ii1 * 64 + d] - x;
            const double cdd = (double)w[ii2 * 64 + d] - x;
            v1 = fma(a, a, v1);
            v2 = fma(cdd, cdd, v2);
        }
        int fin;
        if (v1 < v2)      fin = ii1;
        else if (v2 < v1) fin = ii2;
        else              fin = (ii1 < ii2) ? ii1 : ii2;
        fin_s[rloc] = fin;
        atomicAdd(&hist[fin], 1);
    }
    __syncthreads();

    // ---- quant write (value = chosen code; |diff vs x+(q-x)| ~6e-8)
    //      + fp64 loss partial ----
    double sq = 0.0;
#pragma unroll
    for (int it = 0; it < 16; ++it) {
        const int idx = it * 512 + tid;
        const int d  = idx >> 7;        // 0..63
        const int tt = idx & 127;       // row-local (constant per thread)
        const float q = w[fin_s[tt] * 64 + d];
        const size_t go = (size_t)b * 131072 + (size_t)d * T_SZ + t0 + tt;
        const float x = in[go];
        qout[go] = q;
        const double dd = (double)q - (double)x;
        sq = fma(dd, dd, sq);
    }
    for (int off = 32; off > 0; off >>= 1) sq += __shfl_down(sq, off);
    if (lane == 0) redd[wv] = sq;

    // ---- one-hot rows: wave w writes rows w*16..w*16+16 (float2) ----
#pragma unroll 1
    for (int rr = 0; rr < 16; ++rr) {
        const int rloc = wv * 16 + rr;
        const int f = fin_s[rloc];
        float* ebase = enc + (((size_t)(n0 + rloc)) << 10);
#pragma unroll
        for (int jj = 0; jj < 8; ++jj) {
            const int col = jj * 128 + lane * 2;
            float2 v;
            v.x = (col == f)     ? 1.0f : 0.0f;
            v.y = (col + 1 == f) ? 1.0f : 0.0f;
            *(float2*)(ebase + col) = v;
        }
    }

    __syncthreads();
    if (tid == 0) {
        double s = 0.0;
#pragma unroll
        for (int i = 0; i < 8; ++i) s += redd[i];
        atomicAdd(loss_sum, s);
    }
}

__global__ __launch_bounds__(256) void k_final(const int* __restrict__ hist,
                                               const double* __restrict__ loss_sum,
                                               float* __restrict__ out_loss,
                                               float* __restrict__ out_perp) {
    __shared__ double red[256];
    const int tid = threadIdx.x;
    double h = 0.0;
    for (int k = tid; k < K_CODES; k += 256) {
        const double p = (double)hist[k] / (double)N_ROWS;
        h += p * log(p + 1e-10);
    }
    red[tid] = h;
    __syncthreads();
#pragma unroll
    for (int st = 128; st > 0; st >>= 1) {
        if (tid < st) red[tid] += red[tid + st];
        __syncthreads();
    }
    if (tid == 0) {
        out_perp[0] = (float)exp(-red[0]);
        const double mean = loss_sum[0] / (double)BCT;
        out_loss[0] = (float)(1.25 * mean);  // q_latent + 0.25*e_latent
    }
}

extern "C" void kernel_launch(void* const* d_in, const int* in_sizes, int n_in,
                              void* d_out, int out_size, void* d_ws, size_t ws_size,
                              hipStream_t stream) {
    const float* in = (const float*)d_in[0];
    const float* w  = (const float*)d_in[1];

    float* out      = (float*)d_out;
    float* out_loss = out;                 // [0]
    float* out_q    = out + 1;             // [1, 1+BCT)
    float* out_perp = out + 1 + BCT;       // [1+BCT]
    float* out_enc  = out + 2 + BCT;       // [2+BCT, ...)

    char*   ws       = (char*)d_ws;
    int*    ws_hist  = (int*)ws;
    double* ws_loss  = (double*)(ws + 4096);
    float*  ws_esq   = (float*)(ws + 8192);
    ushort* ws_wpack = (ushort*)(ws + 16384);

    k_prep  <<<4,   256, 0, stream>>>(w, ws_esq, ws_wpack, ws_hist, ws_loss);
    k_argmin<<<256, 512, 0, stream>>>(in, w, ws_esq, ws_wpack, ws_hist,
                                      ws_loss, out_q, out_enc);
    k_final <<<1,   256, 0, stream>>>(ws_hist, ws_loss, out_loss, out_perp);
}

// Round 8
// 188.655 us; speedup vs baseline: 1.5251x; 1.1016x over previous
//
#include <hip/hip_runtime.h>
#include <cstdint>
#include <cstddef>

#define K_CODES 1024
#define D_DIM   64
#define T_SZ    2048
#define N_ROWS  32768
#define BCT     2097152

typedef const __attribute__((address_space(1))) uint32_t* gp1_t;
typedef __attribute__((address_space(3))) uint32_t*       lp3_t;
typedef __attribute__((ext_vector_type(8))) short         short8;  // 8 bf16
typedef __attribute__((ext_vector_type(4))) float         f32x4;
typedef __attribute__((ext_vector_type(4))) int           i32x4;

// ws layout (bytes):
//   [0,     4096):   hist[1024] int     (zeroed by k_prep)
//   [4096,  4104):   loss_sum double    (zeroed by k_prep)
//   [8192,  12288):  esq[1024] float
//   [16384, 540672): Wpack bf16 [64ct][2ks][2hl][64lane][8j] ushort (256KB)

__device__ __forceinline__ ushort bf16_rne(float f) {
    uint32_t u = __builtin_bit_cast(uint32_t, f);
    u += 0x7FFFu + ((u >> 16) & 1u);
    return (ushort)(u >> 16);
}
__device__ __forceinline__ float bf16_f(ushort h) {
    uint32_t u = ((uint32_t)h) << 16;
    return __builtin_bit_cast(float, u);
}

// 8 threads per code: esq (fp64) + W packed into MFMA B-fragment bf16 hi/lo.
__global__ __launch_bounds__(256) void k_prep(const float* __restrict__ w,
                                              float* __restrict__ esq,
                                              ushort* __restrict__ wpack,
                                              int* __restrict__ hist,
                                              double* __restrict__ loss_sum) {
    const int gtid = blockIdx.x * 256 + threadIdx.x;   // 0..8191
    const int k = gtid >> 3, grp = gtid & 7;
    if (gtid < K_CODES) hist[gtid] = 0;
    if (gtid == 0) loss_sum[0] = 0.0;
    const int ct = k >> 4, cl = k & 15;
    double s = 0.0;
#pragma unroll
    for (int jj = 0; jj < 8; ++jj) {
        const int d = grp * 8 + jj;
        const float x = w[k * 64 + d];
        s = fma((double)x, (double)x, s);
        const ushort hi = bf16_rne(x);
        const ushort lo = bf16_rne(x - bf16_f(hi));
        const int ks = d >> 5, g = (d >> 3) & 3, j = d & 7;
        const int lane = g * 16 + cl;
        const size_t base = ((size_t)(ct * 2 + ks)) * 2;
        wpack[((base + 0) * 64 + lane) * 8 + j] = hi;
        wpack[((base + 1) * 64 + lane) * 8 + j] = lo;
    }
    s += __shfl_xor(s, 1); s += __shfl_xor(s, 2); s += __shfl_xor(s, 4);
    if (grp == 0) esq[k] = (float)s;
}

// MFMA mega-kernel: 512 blocks x 256 thr (4 waves) -> 2 blocks/CU.
// Block = 64 rows x all 1024 codes; wave w owns one 16-row A-tile.
// W streamed as 8 x 32KB chunks, double-buffered via global_load_lds.
// Distances via 3 bf16-split MFMAs (err ~1e-7), val = x.w - esq/2 maximized;
// top-2 per row merged over 16 lanes, fp64 recheck decides the index.
__global__ __launch_bounds__(256, 2) void k_argmin(
        const float* __restrict__ in, const float* __restrict__ w,
        const float* __restrict__ esq, const ushort* __restrict__ wpack,
        int* __restrict__ hist, double* __restrict__ loss_sum,
        float* __restrict__ qout, float* __restrict__ enc) {
    __shared__ __align__(16) ushort lds_b[2][16384];   // 2 x 32KB (reused later)
    __shared__ float  lds_esq[K_CODES];                // 4KB
    __shared__ int    smem_i1[64], smem_i2[64];
    __shared__ int    fin_s[64];
    __shared__ double redd[4];

    const int tid  = threadIdx.x;
    const int lane = tid & 63;
    const int wv   = tid >> 6;      // 0..3
    const int cl   = lane & 15;     // col-in-tile / row-in-A-tile
    const int g    = lane >> 4;     // k-group
    const int n0   = blockIdx.x * 64;
    const int b    = n0 >> 11;
    const int t0   = n0 & (T_SZ - 1);

#pragma unroll
    for (int r = 0; r < 4; ++r) lds_esq[r * 256 + tid] = esq[r * 256 + tid];

    // ---- A fragments (row = lane&15, k = g*8+j; same map as B ->
    // shared k-permutation cancels in the contraction) ----
    const int t_row = t0 + wv * 16 + cl;
    short8 ah[2], al[2];
#pragma unroll
    for (int ks = 0; ks < 2; ++ks) {
        short8 h, l;
#pragma unroll
        for (int j = 0; j < 8; ++j) {
            const int d = ks * 32 + g * 8 + j;
            const float x = in[(size_t)b * 131072 + (size_t)d * T_SZ + t_row];
            const ushort hb = bf16_rne(x);
            h[j] = (short)hb;
            l[j] = (short)bf16_rne(x - bf16_f(hb));
        }
        ah[ks] = h;
        al[ks] = l;
    }

#define STAGEW(BUF, CH)                                                        \
    {                                                                          \
        _Pragma("unroll")                                                      \
        for (int r = 0; r < 8; ++r) {                                          \
            const int li = r * 256 + tid;                                      \
            const ushort* gsrc = wpack + (size_t)(CH)*16384 + (size_t)li * 8;  \
            ushort* ldst = &lds_b[BUF][li * 8];                                \
            __builtin_amdgcn_global_load_lds((gp1_t)gsrc, (lp3_t)ldst, 16, 0, 0);\
        }                                                                      \
    }

    STAGEW(0, 0)
    __syncthreads();

    f32x4 m1v = {-1e30f, -1e30f, -1e30f, -1e30f};
    f32x4 m2v = {-1e30f, -1e30f, -1e30f, -1e30f};
    i32x4 i1v = {0, 0, 0, 0};
    i32x4 i2v = {0, 0, 0, 0};

    int buf = 0;
    for (int ch = 0; ch < 8; ++ch) {
        if (ch < 7) STAGEW(buf ^ 1, ch + 1)
#pragma unroll
        for (int ctl = 0; ctl < 8; ++ctl) {
            const int ct = ch * 8 + ctl;
            const int c  = ct * 16 + cl;
            const float e2 = -0.5f * lds_esq[c];
            f32x4 accP = {e2, e2, e2, e2};
            f32x4 accQ = {0.f, 0.f, 0.f, 0.f};
#pragma unroll
            for (int ks = 0; ks < 2; ++ks) {
                const short8 bh = *(const short8*)&lds_b[buf][(((ctl * 2 + ks) * 2 + 0) * 64 + lane) * 8];
                const short8 bl = *(const short8*)&lds_b[buf][(((ctl * 2 + ks) * 2 + 1) * 64 + lane) * 8];
                accP = __builtin_amdgcn_mfma_f32_16x16x32_bf16(ah[ks], bh, accP, 0, 0, 0);
                accQ = __builtin_amdgcn_mfma_f32_16x16x32_bf16(ah[ks], bl, accQ, 0, 0, 0);
                accQ = __builtin_amdgcn_mfma_f32_16x16x32_bf16(al[ks], bh, accQ, 0, 0, 0);
            }
            // top-2 (maximize; ascending c + strict '>' keeps lowest index)
#pragma unroll
            for (int reg = 0; reg < 4; ++reg) {
                const float v = accP[reg] + accQ[reg];
                const bool gt1 = v > m1v[reg];
                const bool gt2 = v > m2v[reg];
                const float nm2 = gt1 ? m1v[reg] : (gt2 ? v : m2v[reg]);
                const int   ni2 = gt1 ? i1v[reg] : (gt2 ? c : i2v[reg]);
                m1v[reg] = gt1 ? v : m1v[reg];
                i1v[reg] = gt1 ? c : i1v[reg];
                m2v[reg] = nm2;
                i2v[reg] = ni2;
            }
        }
        __syncthreads();   // drains STAGE vmcnt + protects buf swap
        buf ^= 1;
    }

    // ---- merge top-2 across the 16 lanes of each col-group ----
#pragma unroll
    for (int off = 1; off < 16; off <<= 1) {
#pragma unroll
        for (int reg = 0; reg < 4; ++reg) {
            const float pm1 = __shfl_xor(m1v[reg], off);
            const int   pi1 = __shfl_xor(i1v[reg], off);
            const float pm2 = __shfl_xor(m2v[reg], off);
            const int   pi2 = __shfl_xor(i2v[reg], off);
            const bool ours = (m1v[reg] > pm1) ||
                              (m1v[reg] == pm1 && i1v[reg] < pi1);
            float nm1, nm2; int ni1, ni2;
            if (ours) {
                nm1 = m1v[reg]; ni1 = i1v[reg];
                const bool pb = (pm1 > m2v[reg]) ||
                                (pm1 == m2v[reg] && pi1 < i2v[reg]);
                nm2 = pb ? pm1 : m2v[reg];
                ni2 = pb ? pi1 : i2v[reg];
            } else {
                nm1 = pm1; ni1 = pi1;
                const bool ob = (m1v[reg] > pm2) ||
                                (m1v[reg] == pm2 && i1v[reg] < pi2);
                nm2 = ob ? m1v[reg] : pm2;
                ni2 = ob ? i1v[reg] : pi2;
            }
            m1v[reg] = nm1; i1v[reg] = ni1;
            m2v[reg] = nm2; i2v[reg] = ni2;
        }
    }
    if (cl == 0) {   // rows g*4+reg of this wave's 16-row tile
#pragma unroll
        for (int reg = 0; reg < 4; ++reg) {
            smem_i1[wv * 16 + g * 4 + reg] = i1v[reg];
            smem_i2[wv * 16 + g * 4 + reg] = i2v[reg];
        }
    }
    __syncthreads();

    // ---- fp64 recheck, 4 lanes per row (16 d each + shfl reduce) ----
    {
        const int rloc = wv * 16 + (lane >> 2);
        const int quar = lane & 3;
        const int ii1 = smem_i1[rloc], ii2 = smem_i2[rloc];
        const int t = t0 + rloc;
        double v1 = 0.0, v2 = 0.0;
#pragma unroll
        for (int j = 0; j < 16; ++j) {
            const int d = quar * 16 + j;
            const double x = (double)in[(size_t)b * 131072 + (size_t)d * T_SZ + t];
            const double a  = (double)w[ii1 * 64 + d] - x;
            const double cc = (double)w[ii2 * 64 + d] - x;
            v1 = fma(a, a, v1);
            v2 = fma(cc, cc, v2);
        }
        v1 += __shfl_xor(v1, 1); v1 += __shfl_xor(v1, 2);
        v2 += __shfl_xor(v2, 1); v2 += __shfl_xor(v2, 2);
        if (quar == 0) {
            int fin;
            if (v1 < v2)      fin = ii1;
            else if (v2 < v1) fin = ii2;
            else              fin = (ii1 < ii2) ? ii1 : ii2;
            fin_s[rloc] = fin;
            atomicAdd(&hist[fin], 1);
        }
    }
    __syncthreads();

    // ---- gather chosen codes into LDS (coalesced), pad 65 vs banks ----
    float* lds_q = (float*)&lds_b[0][0];   // reuse: k-loop done
#pragma unroll
    for (int r = 0; r < 16; ++r) {
        const int idx = r * 256 + tid;     // 0..4095
        const int row = idx >> 6, d = idx & 63;
        lds_q[row * 65 + d] = w[fin_s[row] * 64 + d];
    }
    __syncthreads();

    // ---- quant write (coalesced) + fp64 loss partial ----
    double sq = 0.0;
#pragma unroll
    for (int it = 0; it < 16; ++it) {
        const int idx = it * 256 + tid;
        const int tt = idx & 63, d = idx >> 6;
        const size_t go = (size_t)b * 131072 + (size_t)d * T_SZ + t0 + tt;
        const float x = in[go];
        const float q = lds_q[tt * 65 + d];
        qout[go] = q;
        const double dd = (double)q - (double)x;
        sq = fma(dd, dd, sq);
    }
    for (int off = 32; off > 0; off >>= 1) sq += __shfl_down(sq, off);
    if (lane == 0) redd[wv] = sq;

    // ---- one-hot rows: wave w writes rows w*16..w*16+16 (float2) ----
#pragma unroll 1
    for (int rr = 0; rr < 16; ++rr) {
        const int rloc = wv * 16 + rr;
        const int f = fin_s[rloc];
        float* ebase = enc + (((size_t)(n0 + rloc)) << 10);
#pragma unroll
        for (int jj = 0; jj < 8; ++jj) {
            const int col = jj * 128 + lane * 2;
            float2 v;
            v.x = (col == f)     ? 1.0f : 0.0f;
            v.y = (col + 1 == f) ? 1.0f : 0.0f;
            *(float2*)(ebase + col) = v;
        }
    }

    __syncthreads();
    if (tid == 0) {
        double s = redd[0] + redd[1] + redd[2] + redd[3];
        atomicAdd(loss_sum, s);
    }
}

__global__ __launch_bounds__(256) void k_final(const int* __restrict__ hist,
                                               const double* __restrict__ loss_sum,
                                               float* __restrict__ out_loss,
                                               float* __restrict__ out_perp) {
    __shared__ double red[256];
    const int tid = threadIdx.x;
    double h = 0.0;
    for (int k = tid; k < K_CODES; k += 256) {
        const double p = (double)hist[k] / (double)N_ROWS;
        h += p * log(p + 1e-10);
    }
    red[tid] = h;
    __syncthreads();
#pragma unroll
    for (int st = 128; st > 0; st >>= 1) {
        if (tid < st) red[tid] += red[tid + st];
        __syncthreads();
    }
    if (tid == 0) {
        out_perp[0] = (float)exp(-red[0]);
        const double mean = loss_sum[0] / (double)BCT;
        out_loss[0] = (float)(1.25 * mean);  // q_latent + 0.25*e_latent
    }
}

extern "C" void kernel_launch(void* const* d_in, const int* in_sizes, int n_in,
                              void* d_out, int out_size, void* d_ws, size_t ws_size,
                              hipStream_t stream) {
    const float* in = (const float*)d_in[0];
    const float* w  = (const float*)d_in[1];

    float* out      = (float*)d_out;
    float* out_loss = out;                 // [0]
    float* out_q    = out + 1;             // [1, 1+BCT)
    float* out_perp = out + 1 + BCT;       // [1+BCT]
    float* out_enc  = out + 2 + BCT;       // [2+BCT, ...)

    char*   ws       = (char*)d_ws;
    int*    ws_hist  = (int*)ws;
    double* ws_loss  = (double*)(ws + 4096);
    float*  ws_esq   = (float*)(ws + 8192);
    ushort* ws_wpack = (ushort*)(ws + 16384);

    k_prep  <<<32,  256, 0, stream>>>(w, ws_esq, ws_wpack, ws_hist, ws_loss);
    k_argmin<<<512, 256, 0, stream>>>(in, w, ws_esq, ws_wpack, ws_hist,
                                      ws_loss, out_q, out_enc);
    k_final <<<1,   256, 0, stream>>>(ws_hist, ws_loss, out_loss, out_perp);
}